// Round 1
// baseline (508.137 us; speedup 1.0000x reference)
//
#include <hip/hip_runtime.h>
#include <hip/hip_bf16.h>

#define NN 100000
#define NE 3200000
#define DI 128
#define DH 16

// ---- edge index access: data may be int32 or int64 (JAX x64 flag unknown).
// flag != 0  -> int32 layout: src = w[e], dst = w[NE+e]
// flag == 0  -> int64 layout: src = w[2e] (lo word), dst = w[2(NE+e)]
__device__ __forceinline__ int edge_src(const int* __restrict__ w, int is32, int e) {
    return is32 ? w[e] : w[2 * e];
}
__device__ __forceinline__ int edge_dst(const int* __restrict__ w, int is32, int e) {
    return is32 ? w[NE + e] : w[2 * (NE + e)];
}

// OR-reduce odd 32-bit words of the first 8192 words. int64 data (values <
// 2^32) has zero high words -> flag stays 0. int32 data puts random node ids
// there -> flag becomes nonzero (P[all 4096 are zero] ~ 1e-20480).
__global__ __launch_bounds__(256) void detect_kernel(const unsigned int* __restrict__ w,
                                                     unsigned int* __restrict__ flag) {
    unsigned int v = 0;
    for (int i = threadIdx.x; i < 4096; i += 256) v |= w[2 * i + 1];
    if (v) atomicOr(flag, 1u);
}

__global__ __launch_bounds__(256) void deg_kernel(const int* __restrict__ ew,
                                                  const unsigned int* __restrict__ flag,
                                                  unsigned int* __restrict__ deg) {
    int e = blockIdx.x * 256 + threadIdx.x;
    int is32 = (*flag != 0);
    if (e < NE) {
        int d = edge_dst(ew, is32, e);
        if ((unsigned)d < NN) atomicAdd(&deg[d], 1u);
    }
}

__global__ __launch_bounds__(256) void dinv_kernel(const unsigned int* __restrict__ deg,
                                                   float* __restrict__ dinv) {
    int v = blockIdx.x * 256 + threadIdx.x;
    if (v < NN) dinv[v] = rsqrtf((float)(deg[v] + 1u));  // +1 = self loop
}

// g1[v][j] = (x[v] . W1[:,j]) * dinv[v]   -- 16 nodes per 256-thread block
__global__ __launch_bounds__(256) void gemm1_kernel(const float* __restrict__ x,
                                                    const float* __restrict__ W1,
                                                    const float* __restrict__ dinv,
                                                    float* __restrict__ g) {
    __shared__ float wl[DI * DH];     // 128x16
    __shared__ float xs[16 * 132];    // 16 rows, stride 132 (bank-conflict pad)
    int tid = threadIdx.x;
    int n0 = blockIdx.x * 16;
    for (int i = tid; i < 512; i += 256)                     // W1: 2048 f32
        ((float4*)wl)[i] = ((const float4*)W1)[i];
    for (int i = tid; i < 512; i += 256) {                   // x tile: 16x128
        int ln = i >> 5;
        int k4 = (i & 31) << 2;
        *(float4*)&xs[ln * 132 + k4] =
            *(const float4*)&x[(size_t)(n0 + ln) * DI + k4];
    }
    __syncthreads();
    int ln = tid >> 4, j = tid & 15;
    int v = n0 + ln;
    float acc = 0.f;
#pragma unroll
    for (int k = 0; k < DI; ++k)
        acc += xs[ln * 132 + k] * wl[k * 16 + j];
    g[v * 16 + j] = acc * dinv[v];
}

// acc[dst[e]][f] += g[src[e]][f], one thread per (edge, feature)
__global__ __launch_bounds__(256) void scatter_kernel(const int* __restrict__ ew,
                                                      const unsigned int* __restrict__ flag,
                                                      const float* __restrict__ g,
                                                      float* __restrict__ acc) {
    unsigned int gid = blockIdx.x * 256u + threadIdx.x;
    int e = (int)(gid >> 4);
    int f = (int)(gid & 15u);
    int is32 = (*flag != 0);
    if (e < NE) {
        int s = edge_src(ew, is32, e);
        int d = edge_dst(ew, is32, e);
        if ((unsigned)s < NN && (unsigned)d < NN)
            unsafeAtomicAdd(&acc[d * 16 + f], g[s * 16 + f]);
    }
}

// h1 = tanh(dinv*(acc1+g1)+b1); then g2 = (h1 @ W2) * dinv, overwriting g.
__global__ __launch_bounds__(256) void fin1_gemm2_kernel(const float* __restrict__ acc1,
                                                         const float* __restrict__ dinv,
                                                         const float* __restrict__ b1,
                                                         const float* __restrict__ W2,
                                                         float* __restrict__ g) {
    __shared__ float w2l[16 * 16];
    __shared__ float ht[16 * 17];
    int tid = threadIdx.x;
    w2l[tid] = W2[tid];
    int n0 = blockIdx.x * 16;
    int ln = tid >> 4, j = tid & 15;
    int v = n0 + ln;
    float di = dinv[v];
    float h = tanhf(di * (acc1[v * 16 + j] + g[v * 16 + j]) + b1[j]);
    ht[ln * 17 + j] = h;
    __syncthreads();
    float a = 0.f;
#pragma unroll
    for (int k = 0; k < 16; ++k)
        a += ht[ln * 17 + k] * w2l[k * 16 + j];
    g[v * 16 + j] = a * di;  // safe: this thread read g[v*16+j] before barrier
}

__global__ __launch_bounds__(256) void fin2_kernel(const float* __restrict__ acc2,
                                                   const float* __restrict__ g2,
                                                   const float* __restrict__ dinv,
                                                   const float* __restrict__ b2,
                                                   float* __restrict__ out) {
    int i = blockIdx.x * 256 + threadIdx.x;
    if (i < NN * DH) {
        int v = i >> 4, j = i & 15;
        out[i] = tanhf(dinv[v] * (acc2[i] + g2[i]) + b2[j]);
    }
}

extern "C" void kernel_launch(void* const* d_in, const int* in_sizes, int n_in,
                              void* d_out, int out_size, void* d_ws, size_t ws_size,
                              hipStream_t stream) {
    const float* x  = (const float*)d_in[0];
    const int*   ew = (const int*)d_in[1];   // int32 view; int64 handled via flag
    const float* W1 = (const float*)d_in[2];
    const float* b1 = (const float*)d_in[3];
    const float* W2 = (const float*)d_in[4];
    const float* b2 = (const float*)d_in[5];
    float* out = (float*)d_out;

    char* ws = (char*)d_ws;
    // layout (1 MiB-aligned): [flag @0][deg @1M][acc1 @2M][acc2 @9M]
    //                         [dinv @16M][g @17M] ; total ~23.4 MiB
    unsigned int* flag = (unsigned int*)(ws);
    unsigned int* deg  = (unsigned int*)(ws + (1u << 20));
    float* acc1 = (float*)(ws + (2u << 20));
    float* acc2 = (float*)(ws + (9u << 20));
    float* dinv = (float*)(ws + (16u << 20));
    float* g    = (float*)(ws + (17u << 20));

    hipMemsetAsync(ws, 0, (16u << 20), stream);  // zeros flag, deg, acc1, acc2

    detect_kernel<<<1, 256, 0, stream>>>((const unsigned int*)ew, flag);
    deg_kernel<<<(NE + 255) / 256, 256, 0, stream>>>(ew, flag, deg);
    dinv_kernel<<<(NN + 255) / 256, 256, 0, stream>>>(deg, dinv);
    gemm1_kernel<<<NN / 16, 256, 0, stream>>>(x, W1, dinv, g);
    scatter_kernel<<<NE * 16 / 256, 256, 0, stream>>>(ew, flag, g, acc1);
    fin1_gemm2_kernel<<<NN / 16, 256, 0, stream>>>(acc1, dinv, b1, W2, g);
    scatter_kernel<<<NE * 16 / 256, 256, 0, stream>>>(ew, flag, g, acc2);
    fin2_kernel<<<NN * DH / 256, 256, 0, stream>>>(acc2, g, dinv, b2, out);
}